// Round 4
// baseline (1983.104 us; speedup 1.0000x reference)
//
#include <hip/hip_runtime.h>
#include <stdint.h>

typedef float    f32x4  __attribute__((ext_vector_type(4)));
typedef __bf16   bf16x8 __attribute__((ext_vector_type(8)));
typedef uint16_t u16x8  __attribute__((ext_vector_type(8)));
typedef uint16_t u16x4  __attribute__((ext_vector_type(4)));

static __device__ __forceinline__ f32x4 mfma_bf16(bf16x8 a, bf16x8 b, f32x4 c) {
  return __builtin_amdgcn_mfma_f32_16x16x32_bf16(a, b, c, 0, 0, 0);
}
// fp32 -> bf16 round-to-nearest-even
static __device__ __forceinline__ uint16_t f2bf(float f) {
  uint32_t u = __builtin_bit_cast(uint32_t, f);
  u += 0x7fffu + ((u >> 16) & 1u);
  return (uint16_t)(u >> 16);
}

constexpr int Nrows = 131072;
constexpr int Dk    = 128;
constexpr int Cc    = 1024;
constexpr int BM    = 128;   // rows of x per block
constexpr int BN    = 256;   // output cols per block
constexpr int KB    = 128;   // c-dim step (contraction of GEMM2)
constexpr int NCB   = Cc / BN;                    // 4
constexpr int XBYTES = BM * Dk * 2;               // 32768
constexpr int PBYTES = BM * KB * 2;               // 32768
constexpr int LDS_MAIN = XBYTES + PBYTES + BM * 4;   // 66048 -> 2 blocks/CU
constexpr int LDS_FB   = LDS_MAIN + Cc * 4;          // fallback adds c2[1024]

// ---------------------------------------------------------------------------
// Prep A: centers -> bf16 [C][D], and c2[C] = ||c||^2
// ---------------------------------------------------------------------------
__global__ void prep_cen(const float* __restrict__ cen,
                         uint16_t* __restrict__ cenb,
                         float* __restrict__ c2) {
  const int t = threadIdx.x;
  const int row = blockIdx.x * 16 + (t >> 4);
  const int q = t & 15;
  const float* src = cen + (size_t)row * Dk + q * 8;
  f32x4 v0 = *(const f32x4*)src;
  f32x4 v1 = *(const f32x4*)(src + 4);
  u16x8 h;
  float ss = 0.f;
#pragma unroll
  for (int i = 0; i < 4; ++i) {
    h[i]     = f2bf(v0[i]); ss += v0[i] * v0[i];
    h[i + 4] = f2bf(v1[i]); ss += v1[i] * v1[i];
  }
  *(u16x8*)(cenb + (size_t)row * Dk + q * 8) = h;
  ss += __shfl_xor(ss, 1);
  ss += __shfl_xor(ss, 2);
  ss += __shfl_xor(ss, 4);
  ss += __shfl_xor(ss, 8);
  if (q == 0) c2[row] = ss;
}

// ---------------------------------------------------------------------------
// Prep B: nT[j][c] = bf16(norm[c][j])
// ---------------------------------------------------------------------------
__global__ void prep_nT(const float* __restrict__ nrm, uint16_t* __restrict__ nT) {
  __shared__ float tile[64][65];
  const int jb = blockIdx.x & 15;
  const int cb = blockIdx.x >> 4;
  const int t  = threadIdx.x;
  const int r  = t >> 4;
  const int q  = t & 15;
#pragma unroll
  for (int i = 0; i < 4; ++i) {
    int row = r + i * 16;  // c within tile
    f32x4 v = *(const f32x4*)(nrm + (size_t)(cb * 64 + row) * Cc + jb * 64 + q * 4);
#pragma unroll
    for (int s = 0; s < 4; ++s) tile[row][q * 4 + s] = v[s];
  }
  __syncthreads();
#pragma unroll
  for (int i = 0; i < 4; ++i) {
    int j = r + i * 16;  // j within tile
    u16x4 hs;
#pragma unroll
    for (int s = 0; s < 4; ++s) hs[s] = f2bf(tile[q * 4 + s][j]);
    *(u16x4*)(nT + (size_t)(jb * 64 + j) * Cc + cb * 64 + q * 4) = hs;
  }
}

// ---------------------------------------------------------------------------
// Fused main: per block out[BM x BN]. c-loop (KB=128):
//   GEMM1 cross = x@cen^T (bf16 MFMA) -> P=exp(-g*sqd) -> LDS -> GEMM2 acc+=P@norm
// colb is pinned per XCD-pair (blockIdx%8 -> XCD) so each XCD's L2 keeps one
// hot 512 KB nT slice + 256 KB cenb. Streaming x uses nt loads (no L2 fill);
// out uses plain full-line stores (write-back coalescing, no nt).
// ---------------------------------------------------------------------------
template <int USE_NT>
__global__ __launch_bounds__(512, 4) void nyst_main(
    const float* __restrict__ x, const float* __restrict__ cen,
    const float* __restrict__ gam, const float* __restrict__ nrm,
    const uint16_t* __restrict__ cenb, const float* __restrict__ c2g,
    const uint16_t* __restrict__ nT, float* __restrict__ out) {
  extern __shared__ char smem[];
  char*  xB  = smem;                         // [128][128] bf16, swizzled
  char*  pB  = smem + XBYTES;                // [128][128] bf16, swizzled
  float* x2s = (float*)(smem + XBYTES + PBYTES);  // [128]
  float* c2s = (float*)(smem + LDS_MAIN);         // [1024], fallback only

  const int tid  = threadIdx.x;
  const int lane = tid & 63;
  const int wid  = tid >> 6;
  const int wr   = wid >> 2;  // 0..1
  const int wc   = wid & 3;   // 0..3
  // XCD-pinned decomposition: xcd = blockIdx%8 (measured round-robin mapping).
  // XCD pair {2k,2k+1} owns colb=k; rowb interleaves across the pair.
  const int xcd  = blockIdx.x & 7;
  const int bi   = blockIdx.x >> 3;          // 0..511
  const int colb = xcd >> 1;                 // 0..3
  const int rowb = (bi << 1) | (xcd & 1);    // 0..1023
  const int l15  = lane & 15;
  const int l4   = lane >> 4;

  const float* xblk = x + (size_t)rowb * BM * Dk;

  // ---- stage x tile as bf16 into swizzled LDS (nt loads); fuse x2 row-sums --
#pragma unroll
  for (int it = 0; it < 4; ++it) {
    int ch = tid + it * 512;   // 2048 chunks of 8 elems
    int r  = ch >> 4;          // row 0..127
    int cc = ch & 15;          // 16B chunk in row
    const float* src = xblk + r * Dk + cc * 8;
    f32x4 v0 = __builtin_nontemporal_load((const f32x4*)src);
    f32x4 v1 = __builtin_nontemporal_load((const f32x4*)(src + 4));
    u16x8 hh;
    float ss = 0.f;
#pragma unroll
    for (int i = 0; i < 4; ++i) {
      hh[i]     = f2bf(v0[i]); ss += v0[i] * v0[i];
      hh[i + 4] = f2bf(v1[i]); ss += v1[i] * v1[i];
    }
    int off = (r * 256 + cc * 16) ^ ((r & 7) << 4);
    *(u16x8*)(xB + off) = hh;
    ss += __shfl_xor(ss, 1);
    ss += __shfl_xor(ss, 2);
    ss += __shfl_xor(ss, 4);
    ss += __shfl_xor(ss, 8);
    if ((tid & 15) == 0) x2s[r] = ss;
  }
  if (!USE_NT) {
#pragma unroll
    for (int rr = 0; rr < 2; ++rr) {
      int r = tid + rr * 512;
      const float* src = cen + (size_t)r * Dk;
      float ss = 0.f;
      for (int k = 0; k < Dk / 4; ++k) {
        f32x4 v = *(const f32x4*)(src + 4 * k);
        ss += v[0] * v[0] + v[1] * v[1] + v[2] * v[2] + v[3] * v[3];
      }
      c2s[r] = ss;
    }
  }
  __syncthreads();

  const float ngam = -gam[0];
  f32x4 zero4 = {0.f, 0.f, 0.f, 0.f};
  f32x4 acc[4][4];
#pragma unroll
  for (int m = 0; m < 4; ++m)
#pragma unroll
    for (int n = 0; n < 4; ++n) acc[m][n] = zero4;

  for (int c0 = 0; c0 < Cc; c0 += KB) {
    // ===== GEMM1: cross[128][128] over 8 waves; wave covers cols {16wc, 64+16wc}
    f32x4 cr[2][4];
#pragma unroll
    for (int g = 0; g < 2; ++g)
#pragma unroll
      for (int m = 0; m < 4; ++m) cr[g][m] = zero4;

#pragma unroll
    for (int kk = 0; kk < 4; ++kk) {
      bf16x8 b0, b1;
      if (USE_NT) {
        int c0col = c0 + 16 * wc + l15;
        b0 = *(const bf16x8*)(cenb + (size_t)c0col * Dk + kk * 32 + l4 * 8);
        b1 = *(const bf16x8*)(cenb + (size_t)(c0col + 64) * Dk + kk * 32 + l4 * 8);
      } else {
#pragma unroll
        for (int g = 0; g < 2; ++g) {
          int ccol = c0 + g * 64 + 16 * wc + l15;
          const float* cb_ = cen + (size_t)ccol * Dk + kk * 32 + l4 * 8;
          f32x4 v0 = *(const f32x4*)cb_;
          f32x4 v1 = *(const f32x4*)(cb_ + 4);
          u16x8 tt;
#pragma unroll
          for (int i = 0; i < 4; ++i) { tt[i] = f2bf(v0[i]); tt[i + 4] = f2bf(v1[i]); }
          if (g == 0) b0 = __builtin_bit_cast(bf16x8, tt);
          else        b1 = __builtin_bit_cast(bf16x8, tt);
        }
      }
#pragma unroll
      for (int m = 0; m < 4; ++m) {
        int row = 64 * wr + 16 * m + l15;
        int off = (row * 256 + kk * 64 + l4 * 16) ^ ((row & 7) << 4);
        bf16x8 a = *(const bf16x8*)(xB + off);
        cr[0][m] = mfma_bf16(a, b0, cr[0][m]);
        cr[1][m] = mfma_bf16(a, b1, cr[1][m]);
      }
    }

    // ===== P = exp(-g*max(x2+c2-2cross,0)) -> swizzled LDS (bf16)
    __syncthreads();  // prev GEMM2 done reading pB
#pragma unroll
    for (int g = 0; g < 2; ++g) {
      int ccol = c0 + g * 64 + 16 * wc + l15;
      float c2v = USE_NT ? c2g[ccol] : c2s[ccol];
#pragma unroll
      for (int m = 0; m < 4; ++m) {
#pragma unroll
        for (int r = 0; r < 4; ++r) {
          int row = 64 * wr + 16 * m + l4 * 4 + r;
          float s = fmaxf(fmaf(-2.f, cr[g][m][r], x2s[row] + c2v), 0.f);
          float p = __expf(ngam * s);
          int off = (row * 256 + (g * 64 + 16 * wc + l15) * 2) ^ ((row & 7) << 4);
          *(uint16_t*)(pB + off) = f2bf(p);
        }
      }
    }
    __syncthreads();

    // ===== GEMM2: acc(64x64 per wave) += P @ norm
#pragma unroll
    for (int kk = 0; kk < 4; ++kk) {
      bf16x8 pa[4];
#pragma unroll
      for (int m = 0; m < 4; ++m) {
        int row = 64 * wr + 16 * m + l15;
        int off = (row * 256 + kk * 64 + l4 * 16) ^ ((row & 7) << 4);
        pa[m] = *(const bf16x8*)(pB + off);
      }
      int krow = c0 + kk * 32 + l4 * 8;
#pragma unroll
      for (int n = 0; n < 4; ++n) {
        int j = colb * BN + wc * 64 + 16 * n + l15;
        bf16x8 b;
        if (USE_NT) {
          b = *(const bf16x8*)(nT + (size_t)j * Cc + krow);
        } else {
          u16x8 tt;
#pragma unroll
          for (int i = 0; i < 8; ++i) tt[i] = f2bf(nrm[(size_t)(krow + i) * Cc + j]);
          b = __builtin_bit_cast(bf16x8, tt);
        }
#pragma unroll
        for (int m = 0; m < 4; ++m) acc[m][n] = mfma_bf16(pa[m], b, acc[m][n]);
      }
    }
  }

  // ===== epilogue: LDS bounce (reuse xB+pB as [64][256] f32) -> coalesced
  //       full-line dwordx4 stores (plain, write-back). Halves h: m in {2h,2h+1}.
  float* outBuf = (float*)smem;
  const int orow0 = rowb * BM;
#pragma unroll
  for (int h = 0; h < 2; ++h) {
    __syncthreads();  // pB reads done (h=0) / prev half readers done (h=1)
#pragma unroll
    for (int mh = 0; mh < 2; ++mh) {
      int m = 2 * h + mh;
#pragma unroll
      for (int n = 0; n < 4; ++n) {
#pragma unroll
        for (int r = 0; r < 4; ++r) {
          int rL = wr * 32 + 16 * mh + l4 * 4 + r;
          outBuf[rL * 256 + wc * 64 + 16 * n + l15] = acc[m][n][r];
        }
      }
    }
    __syncthreads();
#pragma unroll
    for (int i = 0; i < 8; ++i) {
      int ch = tid + 512 * i;   // 4096 chunks of 16B
      int rL = ch >> 6;         // 0..63
      int c4 = ch & 63;
      f32x4 v = *(const f32x4*)(outBuf + rL * 256 + c4 * 4);
      int row = 64 * (rL >> 5) + 32 * h + (rL & 31);
      *(f32x4*)(out + (size_t)(orow0 + row) * Cc + colb * BN + c4 * 4) = v;
    }
  }
}

// ---------------------------------------------------------------------------
extern "C" void kernel_launch(void* const* d_in, const int* in_sizes, int n_in,
                              void* d_out, int out_size, void* d_ws, size_t ws_size,
                              hipStream_t stream) {
  const float* x   = (const float*)d_in[0];  // [131072,128]
  const float* cen = (const float*)d_in[1];  // [1024,128]
  const float* gam = (const float*)d_in[2];  // [1]
  const float* nrm = (const float*)d_in[3];  // [1024,1024]
  float* out = (float*)d_out;

  const size_t cenbB = (size_t)Cc * Dk * 2;  // 256 KB
  const size_t c2B   = (size_t)Cc * 4;       // 4 KB
  const size_t nTB   = (size_t)Cc * Cc * 2;  // 2 MB
  const int grid = (Nrows / BM) * NCB;       // 4096

  if (ws_size >= cenbB + c2B + nTB) {
    uint16_t* cenb = (uint16_t*)d_ws;
    float*    c2   = (float*)((char*)d_ws + cenbB);
    uint16_t* nT   = (uint16_t*)((char*)d_ws + cenbB + c2B);
    prep_cen<<<64, 256, 0, stream>>>(cen, cenb, c2);
    prep_nT<<<256, 256, 0, stream>>>(nrm, nT);
    nyst_main<1><<<grid, 512, LDS_MAIN, stream>>>(x, cen, gam, nrm, cenb, c2, nT, out);
  } else {
    nyst_main<0><<<grid, 512, LDS_FB, stream>>>(x, cen, gam, nrm, nullptr, nullptr, nullptr, out);
  }
}

// Round 5
// 1500.399 us; speedup vs baseline: 1.3217x; 1.3217x over previous
//
#include <hip/hip_runtime.h>
#include <stdint.h>

typedef float    f32x4  __attribute__((ext_vector_type(4)));
typedef __bf16   bf16x8 __attribute__((ext_vector_type(8)));
typedef uint16_t u16x8  __attribute__((ext_vector_type(8)));
typedef uint16_t u16x4  __attribute__((ext_vector_type(4)));

static __device__ __forceinline__ f32x4 mfma_bf16(bf16x8 a, bf16x8 b, f32x4 c) {
  return __builtin_amdgcn_mfma_f32_16x16x32_bf16(a, b, c, 0, 0, 0);
}
// fp32 -> bf16 round-to-nearest-even
static __device__ __forceinline__ uint16_t f2bf(float f) {
  uint32_t u = __builtin_bit_cast(uint32_t, f);
  u += 0x7fffu + ((u >> 16) & 1u);
  return (uint16_t)(u >> 16);
}

constexpr int Nrows = 131072;
constexpr int Dk    = 128;
constexpr int Cc    = 1024;
constexpr int BM    = 64;    // rows of x per block (halved vs R4: kills spills)
constexpr int BN    = 256;   // output cols per block
constexpr int KB    = 128;   // c-dim step
constexpr int NCB   = Cc / BN;                 // 4
constexpr int XBYTES = BM * Dk * 2;            // 16384
constexpr int PBYTES = BM * KB * 2;            // 16384
constexpr int LDS_MAIN = XBYTES + PBYTES + BM * 4;  // 33024 (outBuf 32KB reuses this)
constexpr int LDS_FB   = LDS_MAIN + Cc * 4;         // fallback adds c2[1024]

// ---------------------------------------------------------------------------
// Prep A: centers -> bf16 [C][D], and c2[C] = ||c||^2
// ---------------------------------------------------------------------------
__global__ void prep_cen(const float* __restrict__ cen,
                         uint16_t* __restrict__ cenb,
                         float* __restrict__ c2) {
  const int t = threadIdx.x;
  const int row = blockIdx.x * 16 + (t >> 4);
  const int q = t & 15;
  const float* src = cen + (size_t)row * Dk + q * 8;
  f32x4 v0 = *(const f32x4*)src;
  f32x4 v1 = *(const f32x4*)(src + 4);
  u16x8 h;
  float ss = 0.f;
#pragma unroll
  for (int i = 0; i < 4; ++i) {
    h[i]     = f2bf(v0[i]); ss += v0[i] * v0[i];
    h[i + 4] = f2bf(v1[i]); ss += v1[i] * v1[i];
  }
  *(u16x8*)(cenb + (size_t)row * Dk + q * 8) = h;
  ss += __shfl_xor(ss, 1);
  ss += __shfl_xor(ss, 2);
  ss += __shfl_xor(ss, 4);
  ss += __shfl_xor(ss, 8);
  if (q == 0) c2[row] = ss;
}

// ---------------------------------------------------------------------------
// Prep B: nT[j][c] = bf16(norm[c][j])
// ---------------------------------------------------------------------------
__global__ void prep_nT(const float* __restrict__ nrm, uint16_t* __restrict__ nT) {
  __shared__ float tile[64][65];
  const int jb = blockIdx.x & 15;
  const int cb = blockIdx.x >> 4;
  const int t  = threadIdx.x;
  const int r  = t >> 4;
  const int q  = t & 15;
#pragma unroll
  for (int i = 0; i < 4; ++i) {
    int row = r + i * 16;  // c within tile
    f32x4 v = *(const f32x4*)(nrm + (size_t)(cb * 64 + row) * Cc + jb * 64 + q * 4);
#pragma unroll
    for (int s = 0; s < 4; ++s) tile[row][q * 4 + s] = v[s];
  }
  __syncthreads();
#pragma unroll
  for (int i = 0; i < 4; ++i) {
    int j = r + i * 16;  // j within tile
    u16x4 hs;
#pragma unroll
    for (int s = 0; s < 4; ++s) hs[s] = f2bf(tile[q * 4 + s][j]);
    *(u16x4*)(nT + (size_t)(jb * 64 + j) * Cc + cb * 64 + q * 4) = hs;
  }
}

// ---------------------------------------------------------------------------
// Fused main: per block out[64 x 256]. c-loop (KB=128):
//   GEMM1 cross = x@cen^T -> P=exp(-g*sqd) -> LDS -> GEMM2 acc += P@nT
// Per-wave state: acc[2][4]+cr[2][2] = 48 f32 -> fits 128-reg cap, NO SPILLS
// at 2 blocks/CU (the R2-R4 killer). colb pinned per XCD pair for L2 locality.
// ---------------------------------------------------------------------------
template <int USE_NT>
__global__ __launch_bounds__(512, 4) void nyst_main(
    const float* __restrict__ x, const float* __restrict__ cen,
    const float* __restrict__ gam, const float* __restrict__ nrm,
    const uint16_t* __restrict__ cenb, const float* __restrict__ c2g,
    const uint16_t* __restrict__ nT, float* __restrict__ out) {
  extern __shared__ char smem[];
  char*  xB  = smem;                              // [64][128] bf16, swizzled
  char*  pB  = smem + XBYTES;                     // [64][128] bf16, swizzled
  float* x2s = (float*)(smem + XBYTES + PBYTES);  // [64]
  float* c2s = (float*)(smem + LDS_MAIN);         // [1024], fallback only

  const int tid  = threadIdx.x;
  const int lane = tid & 63;
  const int wid  = tid >> 6;
  const int wr   = wid >> 2;  // 0..1  (row half)
  const int wc   = wid & 3;   // 0..3  (col quarter)
  // XCD-pinned decomposition: xcd = blockIdx%8; pair {2k,2k+1} owns colb=k.
  const int xcd  = blockIdx.x & 7;
  const int bi   = blockIdx.x >> 3;          // 0..1023
  const int colb = xcd >> 1;                 // 0..3
  const int rowb = (bi << 1) | (xcd & 1);    // 0..2047
  const int l15  = lane & 15;
  const int l4   = lane >> 4;

  const float* xblk = x + (size_t)rowb * BM * Dk;

  // ---- stage x tile as bf16 into swizzled LDS (nt loads); fuse x2 row-sums --
#pragma unroll
  for (int it = 0; it < 2; ++it) {
    int ch = tid + it * 512;   // 1024 chunks of 8 elems
    int r  = ch >> 4;          // row 0..63
    int cc = ch & 15;          // 16B chunk in row
    const float* src = xblk + r * Dk + cc * 8;
    f32x4 v0 = __builtin_nontemporal_load((const f32x4*)src);
    f32x4 v1 = __builtin_nontemporal_load((const f32x4*)(src + 4));
    u16x8 hh;
    float ss = 0.f;
#pragma unroll
    for (int i = 0; i < 4; ++i) {
      hh[i]     = f2bf(v0[i]); ss += v0[i] * v0[i];
      hh[i + 4] = f2bf(v1[i]); ss += v1[i] * v1[i];
    }
    int off = (r * 256 + cc * 16) ^ ((r & 7) << 4);
    *(u16x8*)(xB + off) = hh;
    ss += __shfl_xor(ss, 1);
    ss += __shfl_xor(ss, 2);
    ss += __shfl_xor(ss, 4);
    ss += __shfl_xor(ss, 8);
    if ((tid & 15) == 0) x2s[r] = ss;
  }
  if (!USE_NT) {
#pragma unroll
    for (int rr = 0; rr < 2; ++rr) {
      int r = tid + rr * 512;
      const float* src = cen + (size_t)r * Dk;
      float ss = 0.f;
      for (int k = 0; k < Dk / 4; ++k) {
        f32x4 v = *(const f32x4*)(src + 4 * k);
        ss += v[0] * v[0] + v[1] * v[1] + v[2] * v[2] + v[3] * v[3];
      }
      c2s[r] = ss;
    }
  }
  __syncthreads();

  const float ngam = -gam[0];
  f32x4 zero4 = {0.f, 0.f, 0.f, 0.f};
  f32x4 acc[2][4];
#pragma unroll
  for (int m = 0; m < 2; ++m)
#pragma unroll
    for (int n = 0; n < 4; ++n) acc[m][n] = zero4;

  for (int c0 = 0; c0 < Cc; c0 += KB) {
    // ===== GEMM1: cross[64][128]; wave: rows 32wr..+31, cols {16wc, 64+16wc}
    f32x4 cr[2][2];  // [g][m]
#pragma unroll
    for (int g = 0; g < 2; ++g)
#pragma unroll
      for (int m = 0; m < 2; ++m) cr[g][m] = zero4;

#pragma unroll
    for (int kk = 0; kk < 4; ++kk) {
      bf16x8 b0, b1;
      if (USE_NT) {
        int c0col = c0 + 16 * wc + l15;
        b0 = *(const bf16x8*)(cenb + (size_t)c0col * Dk + kk * 32 + l4 * 8);
        b1 = *(const bf16x8*)(cenb + (size_t)(c0col + 64) * Dk + kk * 32 + l4 * 8);
      } else {
#pragma unroll
        for (int g = 0; g < 2; ++g) {
          int ccol = c0 + g * 64 + 16 * wc + l15;
          const float* cb_ = cen + (size_t)ccol * Dk + kk * 32 + l4 * 8;
          f32x4 v0 = *(const f32x4*)cb_;
          f32x4 v1 = *(const f32x4*)(cb_ + 4);
          u16x8 tt;
#pragma unroll
          for (int i = 0; i < 4; ++i) { tt[i] = f2bf(v0[i]); tt[i + 4] = f2bf(v1[i]); }
          if (g == 0) b0 = __builtin_bit_cast(bf16x8, tt);
          else        b1 = __builtin_bit_cast(bf16x8, tt);
        }
      }
#pragma unroll
      for (int m = 0; m < 2; ++m) {
        int row = 32 * wr + 16 * m + l15;
        int off = (row * 256 + kk * 64 + l4 * 16) ^ ((row & 7) << 4);
        bf16x8 a = *(const bf16x8*)(xB + off);
        cr[0][m] = mfma_bf16(a, b0, cr[0][m]);
        cr[1][m] = mfma_bf16(a, b1, cr[1][m]);
      }
    }

    // ===== P = exp(-g*max(x2+c2-2cross,0)) -> swizzled LDS (bf16)
    __syncthreads();  // prev GEMM2 done reading pB
#pragma unroll
    for (int g = 0; g < 2; ++g) {
      int ccol = c0 + g * 64 + 16 * wc + l15;
      float c2v = USE_NT ? c2g[ccol] : c2s[ccol];
#pragma unroll
      for (int m = 0; m < 2; ++m) {
#pragma unroll
        for (int r = 0; r < 4; ++r) {
          int row = 32 * wr + 16 * m + l4 * 4 + r;
          float s = fmaxf(fmaf(-2.f, cr[g][m][r], x2s[row] + c2v), 0.f);
          float p = __expf(ngam * s);
          int off = (row * 256 + (g * 64 + 16 * wc + l15) * 2) ^ ((row & 7) << 4);
          *(uint16_t*)(pB + off) = f2bf(p);
        }
      }
    }
    __syncthreads();

    // ===== GEMM2: acc(32x64 per wave) += P @ nT
#pragma unroll
    for (int kk = 0; kk < 4; ++kk) {
      bf16x8 pa[2];
#pragma unroll
      for (int m = 0; m < 2; ++m) {
        int row = 32 * wr + 16 * m + l15;
        int off = (row * 256 + kk * 64 + l4 * 16) ^ ((row & 7) << 4);
        pa[m] = *(const bf16x8*)(pB + off);
      }
      int krow = c0 + kk * 32 + l4 * 8;
#pragma unroll
      for (int n = 0; n < 4; ++n) {
        int j = colb * BN + wc * 64 + 16 * n + l15;
        bf16x8 b;
        if (USE_NT) {
          b = *(const bf16x8*)(nT + (size_t)j * Cc + krow);
        } else {
          u16x8 tt;
#pragma unroll
          for (int i = 0; i < 8; ++i) tt[i] = f2bf(nrm[(size_t)(krow + i) * Cc + j]);
          b = __builtin_bit_cast(bf16x8, tt);
        }
        acc[0][n] = mfma_bf16(pa[0], b, acc[0][n]);
        acc[1][n] = mfma_bf16(pa[1], b, acc[1][n]);
      }
    }
  }

  // ===== epilogue: LDS bounce (reuse xB+pB as [32][256] f32), halves by wr ==
  float* outBuf = (float*)smem;
  const int orow0 = rowb * BM;
#pragma unroll
  for (int h = 0; h < 2; ++h) {
    __syncthreads();  // pB reads done (h=0) / prev half readers done (h=1)
    if (wr == h) {
#pragma unroll
      for (int m = 0; m < 2; ++m) {
#pragma unroll
        for (int n = 0; n < 4; ++n) {
#pragma unroll
          for (int r = 0; r < 4; ++r) {
            int rL = 16 * m + l4 * 4 + r;  // 0..31
            outBuf[rL * 256 + wc * 64 + 16 * n + l15] = acc[m][n][r];
          }
        }
      }
    }
    __syncthreads();
#pragma unroll
    for (int i = 0; i < 4; ++i) {
      int ch = tid + 512 * i;   // 2048 chunks of 16B
      int rL = ch >> 6;         // 0..31
      int c4 = ch & 63;
      f32x4 v = *(const f32x4*)(outBuf + rL * 256 + c4 * 4);
      *(f32x4*)(out + (size_t)(orow0 + 32 * h + rL) * Cc + colb * BN + c4 * 4) = v;
    }
  }
}

// ---------------------------------------------------------------------------
extern "C" void kernel_launch(void* const* d_in, const int* in_sizes, int n_in,
                              void* d_out, int out_size, void* d_ws, size_t ws_size,
                              hipStream_t stream) {
  const float* x   = (const float*)d_in[0];  // [131072,128]
  const float* cen = (const float*)d_in[1];  // [1024,128]
  const float* gam = (const float*)d_in[2];  // [1]
  const float* nrm = (const float*)d_in[3];  // [1024,1024]
  float* out = (float*)d_out;

  const size_t cenbB = (size_t)Cc * Dk * 2;  // 256 KB
  const size_t c2B   = (size_t)Cc * 4;       // 4 KB
  const size_t nTB   = (size_t)Cc * Cc * 2;  // 2 MB
  const int grid = (Nrows / BM) * NCB;       // 8192

  if (ws_size >= cenbB + c2B + nTB) {
    uint16_t* cenb = (uint16_t*)d_ws;
    float*    c2   = (float*)((char*)d_ws + cenbB);
    uint16_t* nT   = (uint16_t*)((char*)d_ws + cenbB + c2B);
    prep_cen<<<64, 256, 0, stream>>>(cen, cenb, c2);
    prep_nT<<<256, 256, 0, stream>>>(nrm, nT);
    nyst_main<1><<<grid, 512, LDS_MAIN, stream>>>(x, cen, gam, nrm, cenb, c2, nT, out);
  } else {
    nyst_main<0><<<grid, 512, LDS_FB, stream>>>(x, cen, gam, nrm, nullptr, nullptr, nullptr, out);
  }
}